// Round 15
// baseline (452.840 us; speedup 1.0000x reference)
//
#include <hip/hip_runtime.h>
#include <hip/hip_bf16.h>

#define Lc 4
#define Nc 50000
#define Ec 800000
#define Bc 16384
#define EDc 256
#define Kc 7
#define Mtot (Lc * Nc)      // 200000 nodes total
#define KDIM (EDc * Kc)     // 1792

#define NWRD 6272           // bitmap words for Mtot bits
#define SMAX 32768          // max sampled (layer,node) pairs
#define CAP2 64             // csr slots per sampled node (deg>64 prob ~1e-13)
#define EB 3125             // edge blocks (Ec/256)

#define PADTOT 33024        // 32768 sides + per-layer pad to 64
#define PADBIT (1 << 24)

typedef __attribute__((ext_vector_type(8))) short bf16x8;
typedef __attribute__((ext_vector_type(4))) float f32x4;

static __device__ __forceinline__ unsigned short f2bf(float f) {
    unsigned u = __float_as_uint(f);
    unsigned r = (u + 0x7fffu + ((u >> 16) & 1u)) >> 16;
    return (unsigned short)r;
}
static __device__ __forceinline__ float bf2f(unsigned short u) {
    return __uint_as_float(((unsigned)u) << 16);
}

// ---------------- prep: weight transposes + scratch zero -------------------

__global__ void k_prep(const float* __restrict__ conv_w, unsigned short* __restrict__ wbt,
                       const float* __restrict__ W2, unsigned short* __restrict__ w2t,
                       int* __restrict__ zeroRegion, int zn) {
    int bb = blockIdx.x;
    if (bb < 1792) {
        int i = bb * 256 + threadIdx.x;       // 458752
        int co = i / KDIM;
        int r = i % KDIM;
        int ci = r / Kc, k = r % Kc;
        wbt[(size_t)co * KDIM + k * EDc + ci] = f2bf(conv_w[i]);
    } else {
        int i = (bb - 1792) * 256 + threadIdx.x;  // 0..65535
        for (int z = i; z < zn; z += 65536) zeroRegion[z] = 0;
        if (i < 32768) {
            int l = i >> 13, r = i & 8191;
            int d = r >> 6, h = r & 63;
            w2t[i] = f2bf(W2[(size_t)(l * 64 + h) * 128 + d]);
        }
    }
}

// mark sampled (layer,node) bitmap + per-layer sample counts + init ord
__global__ void k_mark(const int* __restrict__ now, const int* __restrict__ lnn,
                       const int* __restrict__ rnn, int* __restrict__ ord,
                       unsigned* __restrict__ bitmap, int* __restrict__ gcnt) {
    int b = blockIdx.x * 256 + threadIdx.x;   // exactly 16384 threads
    for (int p = b; p < PADTOT; p += 16384) ord[p] = PADBIT;
    int l = now[b];
    int a1 = l * Nc + lnn[b];
    atomicOr(&bitmap[a1 >> 5], 1u << (a1 & 31));
    int a2 = l * Nc + rnn[b];
    atomicOr(&bitmap[a2 >> 5], 1u << (a2 & 31));
    int lane = threadIdx.x & 63;
#pragma unroll
    for (int ll = 0; ll < 4; ll++) {
        unsigned long long m = __ballot(l == ll);
        if (m && lane == __builtin_ctzll(m)) atomicAdd(&gcnt[ll], __popcll(m));
    }
}

// degree count (direct int atomics) + bitmap rank scan (extra block)
__global__ void k_degrank(const int* __restrict__ ei, int* __restrict__ cnt,
                          const unsigned* __restrict__ bitmap, int* __restrict__ rankBase) {
    __shared__ int wsum[4];
    if (blockIdx.x == EB) {          // rank block
        if (blockIdx.y != 0) return;
        const int PW = 25;           // 256*25 = 6400 >= NWRD
        int t = threadIdx.x;
        int s = 0;
        for (int j = 0; j < PW; j++) {
            int idx = t * PW + j;
            if (idx < NWRD) s += __popc(bitmap[idx]);
        }
        int lane = t & 63, wv = t >> 6;
        int x = s;
#pragma unroll
        for (int off = 1; off < 64; off <<= 1) {
            int y = __shfl_up(x, off);
            if (lane >= off) x += y;
        }
        if (lane == 63) wsum[wv] = x;
        __syncthreads();
        int carry = 0;
        for (int w = 0; w < wv; w++) carry += wsum[w];
        int run = x - s + carry;     // exclusive prefix for this thread
        for (int j = 0; j < PW; j++) {
            int idx = t * PW + j;
            if (idx < NWRD) { rankBase[idx] = run; run += __popc(bitmap[idx]); }
        }
        return;
    }
    int l = blockIdx.y;
    int e = blockIdx.x * 256 + threadIdx.x;
    if (e < Ec) atomicAdd(&cnt[l * Nc + ei[(size_t)l * 2 * Ec + Ec + e]], 1);
}

// per-node: dis = rsqrt(deg+1), g = dis * x   (x_nodes is flat [Mtot])
__global__ void k_nodeprep(const int* __restrict__ cnt, const float* __restrict__ x_nodes,
                           float* __restrict__ dis, float* __restrict__ g) {
    int i = blockIdx.x * 256 + threadIdx.x;
    if (i < Mtot) {
        float dn = rsqrtf((float)cnt[i] + 1.0f);
        dis[i] = dn;
        g[i] = dn * x_nodes[i];
    }
}

// one edge pass: s-accumulation (fp32 HW atomics) + bitmap-filtered csr fill
__global__ void k_edge2(const int* __restrict__ ei, const float* __restrict__ g,
                        const unsigned* __restrict__ bitmap, const int* __restrict__ rankBase,
                        float* __restrict__ sacc, int* __restrict__ cursor,
                        int* __restrict__ csr2) {
    int l = blockIdx.y;
    int e = blockIdx.x * 256 + threadIdx.x;
    if (e >= Ec) return;
    const int* srcp = ei + (size_t)l * 2 * Ec;
    int sv = srcp[e];
    int d = srcp[Ec + e];
    int n4 = l * Nc + d;
    unsafeAtomicAdd(&sacc[n4], g[l * Nc + sv]);
    unsigned w = bitmap[n4 >> 5];
    unsigned bit = 1u << (n4 & 31);
    if (w & bit) {                   // sampled dst: record edge in fixed slots
        int ridx = rankBase[n4 >> 5] + __popc(w & (bit - 1));
        int slot = atomicAdd(&cursor[ridx], 1);
        if (slot < CAP2) csr2[(size_t)ridx * CAP2 + slot] = sv;
    }
}

// finalize s + BN stats; packs ns = (dis, s)
__global__ void k_sfin(const float* __restrict__ sacc, const float* __restrict__ dis,
                       const float* __restrict__ g, float2* __restrict__ ns,
                       double* __restrict__ stats) {
    int l = blockIdx.y;
    int n = blockIdx.x * 256 + threadIdx.x;
    double v = 0.0, v2 = 0.0;
    if (n < Nc) {
        int n4 = l * Nc + n;
        float dn = dis[n4];
        float sf = dn * (sacc[n4] + g[n4]);   // neighbors + self loop
        ns[n4] = make_float2(dn, sf);
        v = (double)sf;
        v2 = (double)sf * (double)sf;
    }
    for (int m = 32; m; m >>= 1) { v += __shfl_xor(v, m); v2 += __shfl_xor(v2, m); }
    __shared__ double r0[4], r1[4];
    int wid = threadIdx.x >> 6, lane = threadIdx.x & 63;
    if (lane == 0) { r0[wid] = v; r1[wid] = v2; }
    __syncthreads();
    if (threadIdx.x == 0) {
        atomicAdd(&stats[l * 2 + 0], r0[0] + r0[1] + r0[2] + r0[3]);
        atomicAdd(&stats[l * 2 + 1], r1[0] + r1[1] + r1[2] + r1[3]);
    }
}

// ---------------- side ordering + BN coefficient vector (fused) ------------

__global__ __launch_bounds__(256) void k_ordcvec(const int* __restrict__ now,
        const int* __restrict__ gcnt, int* __restrict__ gcur, int* __restrict__ ord,
        const double* __restrict__ stats, const float* __restrict__ W1,
        const float* __restrict__ gamma, float* __restrict__ cbuf) {
    if (blockIdx.x == 64) {          // cvec block
        int l = threadIdx.x >> 6, h = threadIdx.x & 63;
        double mean = stats[l * 2] / (double)Nc;
        double var = stats[l * 2 + 1] / (double)Nc - mean * mean;
        float w = W1[l * 64 + h];
        cbuf[l * 72 + h] = gamma[l * 64 + h] * w * rsqrtf((float)var * w * w + 1e-5f);
        if (h == 0) cbuf[l * 72 + 64] = (float)mean;
        return;
    }
    int b = blockIdx.x * 256 + threadIdx.x;   // exactly 16384
    int l = now[b];
    int segBase = 0;
    for (int ll = 0; ll < l; ll++) segBase += (2 * gcnt[ll] + 63) & ~63;
    int lane = threadIdx.x & 63;
#pragma unroll
    for (int ll = 0; ll < 4; ll++) {
        unsigned long long m = __ballot(l == ll);
        if (!m) continue;
        int ldr = __builtin_ctzll(m);
        int bs = 0;
        if (lane == ldr) bs = atomicAdd(&gcur[ll], __popcll(m));
        bs = __shfl(bs, ldr);
        if (l == ll) {
            int rk = __popcll(m & (lane ? ((1ull << lane) - 1) : 0ull));
            int sp = segBase + 2 * (bs + rk);
            ord[sp] = (2 * b) | (ll << 20);
            ord[sp + 1] = (2 * b + 1) | (ll << 20);
        }
    }
}

// ---------------- per-side aggregation (lane-parallel, single pass) --------

__global__ __launch_bounds__(256) void k_agg(const int* __restrict__ ord,
        const int* __restrict__ lnn, const int* __restrict__ rnn,
        const int* __restrict__ cnt, const int* __restrict__ csr2,
        const int* __restrict__ rankBase, const unsigned* __restrict__ bitmap,
        const float2* __restrict__ ns, const float* __restrict__ cbuf,
        const float* __restrict__ beta, unsigned short* __restrict__ acch) {
    int pos = blockIdx.x * 4 + (threadIdx.x >> 6);
    int lane = threadIdx.x & 63;
    int ordv = ord[pos];
    if (ordv & PADBIT) { acch[(size_t)pos * 64 + lane] = 0; return; }
    int side = ordv & 0xFFFFF;
    int l = (ordv >> 20) & 3;
    int b = side >> 1;
    int n = (side & 1) ? rnn[b] : lnn[b];
    int n4 = l * Nc + n;
    float c = cbuf[l * 72 + lane], mu = cbuf[l * 72 + 64], bt = beta[l * 64 + lane];
    const float2* nsl = ns + (size_t)l * Nc;
    unsigned w = bitmap[n4 >> 5];
    unsigned bit = 1u << (n4 & 31);
    int ridx = rankBase[n4 >> 5] + __popc(w & (bit - 1));
    int deg = min(cnt[n4], CAP2);
    float a = 0.f;
    int sv = (lane < deg) ? csr2[(size_t)ridx * CAP2 + lane] : 0;
    float nv = 0.f, fv = 0.f;
    if (lane < deg) {
        float2 nf = nsl[sv];                     // 64 parallel gathers
        nv = nf.x; fv = nf.y;
    }
    for (int j = 0; j < deg; j++) {
        float nj = __shfl(nv, j);
        float fj = __shfl(fv, j);
        a += nj * fmaxf(c * (fj - mu) + bt, 0.f);
    }
    float2 nself = ns[n4];
    float hs = fmaxf(c * (nself.y - mu) + bt, 0.f);
    a = nself.x * a + nself.x * nself.x * hs;
    acch[(size_t)pos * 64 + lane] = f2bf(a);
}

// batched MFMA GEMM: [PADTOT x 64] @ W2[l][64 x 128] -> lsh (bf16)
__global__ __launch_bounds__(256) void k_embgemm(const unsigned short* __restrict__ acch,
        const int* __restrict__ ord, const unsigned short* __restrict__ w2t,
        const float* __restrict__ b2, unsigned short* __restrict__ lsh) {
    int t0 = blockIdx.x * 16;
    int wn = threadIdx.x >> 6, lane = threadIdx.x & 63;
    int lrow = lane & 15, lg = lane >> 4;
    int l = (ord[t0] >> 20) & 3;     // uniform layer for all valid rows in tile
    const unsigned short* ap = acch + (size_t)(t0 + lrow) * 64 + lg * 8;
    const unsigned short* bp = w2t + (size_t)(l * 128 + wn * 32 + lrow) * 64 + lg * 8;
    f32x4 acc[2] = {};
#pragma unroll
    for (int kt = 0; kt < 2; kt++) {
        bf16x8 a = *(const bf16x8*)(ap + kt * 32);
        bf16x8 b0 = *(const bf16x8*)(bp + kt * 32);
        bf16x8 b1 = *(const bf16x8*)(bp + 16 * 64 + kt * 32);
        acc[0] = __builtin_amdgcn_mfma_f32_16x16x32_bf16(a, b0, acc[0], 0, 0, 0);
        acc[1] = __builtin_amdgcn_mfma_f32_16x16x32_bf16(a, b1, acc[1], 0, 0, 0);
    }
#pragma unroll
    for (int r = 0; r < 4; r++) {
        int pos = t0 + lg * 4 + r;
        int ordv = ord[pos];
        if (ordv & PADBIT) continue;
        int side = ordv & 0xFFFFF;
        size_t base = (size_t)(side >> 1) * 256 + (side & 1) * 128;
#pragma unroll
        for (int ni = 0; ni < 2; ni++) {
            int n = wn * 32 + ni * 16 + lrow;
            lsh[base + n] = f2bf(acc[ni][r] + b2[l * 128 + n]);
        }
    }
}

// ---------------- conv1d MFMA GEMM (round-8 structure) ---------------------

__global__ __launch_bounds__(512, 1) void k_convmma(const unsigned short* __restrict__ lsh,
                                                    const unsigned short* __restrict__ wbt,
                                                    const float* __restrict__ cb,
                                                    float* __restrict__ sh) {
    __shared__ unsigned short lsa[70 * EDc];   // 35840 B
    int b0 = blockIdx.x * 64;
    int wid = threadIdx.x >> 6, lane = threadIdx.x & 63;
    int lrow = lane & 15, lg = lane >> 4;

    for (int idx = threadIdx.x; idx < 70 * 32; idx += 512) {
        int r = idx >> 5, c = idx & 31;
        int grow = b0 - 3 + r;
        uint4 v = make_uint4(0u, 0u, 0u, 0u);
        if ((unsigned)grow < (unsigned)Bc)
            v = *(const uint4*)(lsh + (size_t)grow * EDc + c * 8);
        int byte = (r * 512 + c * 16) ^ ((r & 7) << 4);
        *(uint4*)((char*)lsa + byte) = v;
    }
    __syncthreads();

    const unsigned short* w0 = wbt + (size_t)(wid * 32 + lrow) * KDIM + lg * 8;

    f32x4 acc[4][2] = {};
    bf16x8 br0[8][2], br1[8][2];

#pragma unroll
    for (int tt = 0; tt < 8; tt++)
#pragma unroll
        for (int ni = 0; ni < 2; ni++)
            br0[tt][ni] = *(const bf16x8*)(w0 + ni * 16 * KDIM + tt * 32);

#pragma unroll
    for (int k = 0; k < Kc; k++) {
        if (k < Kc - 1) {
#pragma unroll
            for (int tt = 0; tt < 8; tt++)
#pragma unroll
                for (int ni = 0; ni < 2; ni++) {
                    bf16x8 v = *(const bf16x8*)(w0 + ni * 16 * KDIM + (k + 1) * 256 + tt * 32);
                    if (k & 1) br0[tt][ni] = v; else br1[tt][ni] = v;
                }
        }
#pragma unroll
        for (int tt = 0; tt < 8; tt++) {
            bf16x8 a[4];
#pragma unroll
            for (int mi = 0; mi < 4; mi++) {
                int l = mi * 16 + lrow + k;
                a[mi] = *(const bf16x8*)((const char*)lsa + l * 512
                        + ((lg * 16 + tt * 64) ^ ((l & 7) << 4)));
            }
#pragma unroll
            for (int mi = 0; mi < 4; mi++)
#pragma unroll
                for (int ni = 0; ni < 2; ni++) {
                    bf16x8 bv = (k & 1) ? br1[tt][ni] : br0[tt][ni];
                    acc[mi][ni] = __builtin_amdgcn_mfma_f32_16x16x32_bf16(
                        a[mi], bv, acc[mi][ni], 0, 0, 0);
                }
        }
    }

#pragma unroll
    for (int mi = 0; mi < 4; mi++) {
        int rbase = b0 + mi * 16 + lg * 4;
#pragma unroll
        for (int ni = 0; ni < 2; ni++) {
            int co = wid * 32 + ni * 16 + lrow;
            float bias = cb[co];
#pragma unroll
            for (int r = 0; r < 4; r++)
                sh[(size_t)(rbase + r) * EDc + co] = fmaxf(acc[mi][ni][r] + bias, 0.0f);
        }
    }
}

// 4 samples per 256-thread block (wave = one sample)
__global__ __launch_bounds__(256) void k_final(const unsigned short* __restrict__ lsh,
                        const float* __restrict__ sh,
                        const float* __restrict__ lc_w, const float* __restrict__ lc_b,
                        const float* __restrict__ link_w, const float* __restrict__ link_b,
                        float* __restrict__ out) {
    int b = blockIdx.x * 4 + (threadIdx.x >> 6);
    int lane = threadIdx.x & 63;
    float lsv[4], shv[4];
    float dot = 0.f, nrm = 0.f;
#pragma unroll
    for (int i = 0; i < 4; i++) {
        int ci = lane + i * 64;
        lsv[i] = bf2f(lsh[(size_t)b * 256 + ci]);
        shv[i] = sh[(size_t)b * 256 + ci];
        dot += lsv[i] * shv[i];
        nrm += shv[i] * shv[i];
    }
    for (int m = 32; m; m >>= 1) { dot += __shfl_xor(dot, m); nrm += __shfl_xor(nrm, m); }
    float coef = dot / (nrm + 1e-12f);
    float p0 = 0.f, p1 = 0.f, d0 = 0.f, d1 = 0.f, d2 = 0.f, d3 = 0.f;
#pragma unroll
    for (int i = 0; i < 4; i++) {
        int ci = lane + i * 64;
        float e = lsv[i] - coef * shv[i] + shv[i];
        p0 += e * link_w[ci * 2];
        p1 += e * link_w[ci * 2 + 1];
        d0 += shv[i] * lc_w[ci * 4];
        d1 += shv[i] * lc_w[ci * 4 + 1];
        d2 += shv[i] * lc_w[ci * 4 + 2];
        d3 += shv[i] * lc_w[ci * 4 + 3];
    }
    for (int m = 32; m; m >>= 1) {
        p0 += __shfl_xor(p0, m); p1 += __shfl_xor(p1, m);
        d0 += __shfl_xor(d0, m); d1 += __shfl_xor(d1, m);
        d2 += __shfl_xor(d2, m); d3 += __shfl_xor(d3, m);
    }
    if (lane == 0) {
        out[b * 2]     = p0 + link_b[0];
        out[b * 2 + 1] = p1 + link_b[1];
        float* dd = out + 2 * Bc;
        dd[b * 4]     = d0 + lc_b[0];
        dd[b * 4 + 1] = d1 + lc_b[1];
        dd[b * 4 + 2] = d2 + lc_b[2];
        dd[b * 4 + 3] = d3 + lc_b[3];
    }
}

// ---------------- launch ----------------

extern "C" void kernel_launch(void* const* d_in, const int* in_sizes, int n_in,
                              void* d_out, int out_size, void* d_ws, size_t ws_size,
                              hipStream_t stream) {
    const float* x_nodes    = (const float*)d_in[0];
    const int*   edge_index = (const int*)d_in[1];
    const float* W1   = (const float*)d_in[2];
    // d_in[3] = b1 (cancels in BN)
    const float* gamma = (const float*)d_in[4];
    const float* beta  = (const float*)d_in[5];
    const float* W2   = (const float*)d_in[6];
    const float* b2   = (const float*)d_in[7];
    const float* conv_w = (const float*)d_in[8];
    const float* conv_b = (const float*)d_in[9];
    const float* lc_w   = (const float*)d_in[10];
    const float* lc_b   = (const float*)d_in[11];
    const float* link_w = (const float*)d_in[12];
    const float* link_b = (const float*)d_in[13];
    const int* now = (const int*)d_in[14];
    const int* ln  = (const int*)d_in[15];
    const int* rn  = (const int*)d_in[16];
    float* out = (float*)d_out;

    char* base = (char*)d_ws;
    size_t off = 0;
    auto carve = [&](size_t bytes) {
        void* p = base + off;
        off = (off + bytes + 255) & ~(size_t)255;
        return p;
    };
    // zero region (zeroed in k_prep): cnt .. stats
    int*      cnt    = (int*)carve((size_t)Mtot * 4);
    float*    sacc   = (float*)carve((size_t)Mtot * 4);
    int*      cursor = (int*)carve((size_t)SMAX * 4);
    unsigned* bitmap = (unsigned*)carve((size_t)NWRD * 4);
    int*      gcnt   = (int*)carve(4 * 4);
    int*      gcur   = (int*)carve(4 * 4);
    double*   stats  = (double*)carve(8 * 8);
    // rest
    int*    rankBase = (int*)carve((size_t)(NWRD + 32) * 4);
    int*    csr2     = (int*)carve((size_t)SMAX * CAP2 * 4);
    float*  dis      = (float*)carve((size_t)Mtot * 4);
    float*  g        = (float*)carve((size_t)Mtot * 4);
    float2* ns       = (float2*)carve((size_t)Mtot * 8);
    float*  cbuf     = (float*)carve(Lc * 72 * 4);
    int*    ord      = (int*)carve((size_t)PADTOT * 4);
    unsigned short* acch = (unsigned short*)carve((size_t)PADTOT * 64 * 2);
    float*  shb      = (float*)carve((size_t)Bc * 256 * 4);
    unsigned short* lsh = (unsigned short*)carve((size_t)Bc * 256 * 2);
    unsigned short* wbt = (unsigned short*)carve((size_t)EDc * KDIM * 2);
    unsigned short* w2t = (unsigned short*)carve((size_t)Lc * 128 * 64 * 2);
    (void)ws_size;

    int zn = (int)(((char*)(stats + 8) - (char*)cnt) / 4);

    k_prep<<<2048, 256, 0, stream>>>(conv_w, wbt, W2, w2t, cnt, zn);
    k_mark<<<64, 256, 0, stream>>>(now, ln, rn, ord, bitmap, gcnt);
    k_degrank<<<dim3(EB + 1, Lc), 256, 0, stream>>>(edge_index, cnt, bitmap, rankBase);
    k_nodeprep<<<(Mtot + 255) / 256, 256, 0, stream>>>(cnt, x_nodes, dis, g);
    k_edge2<<<dim3(EB, Lc), 256, 0, stream>>>(edge_index, g, bitmap, rankBase,
                                              sacc, cursor, csr2);
    k_sfin<<<dim3(196, Lc), 256, 0, stream>>>(sacc, dis, g, ns, stats);
    k_ordcvec<<<65, 256, 0, stream>>>(now, gcnt, gcur, ord, stats, W1, gamma, cbuf);
    k_agg<<<PADTOT / 4, 256, 0, stream>>>(ord, ln, rn, cnt, csr2, rankBase, bitmap,
                                          ns, cbuf, beta, acch);
    k_embgemm<<<PADTOT / 16, 256, 0, stream>>>(acch, ord, w2t, b2, lsh);
    k_convmma<<<Bc / 64, 512, 0, stream>>>(lsh, wbt, conv_b, shb);
    k_final<<<Bc / 4, 256, 0, stream>>>(lsh, shb, lc_w, lc_b, link_w, link_b, out);
}

// Round 16
// 184.818 us; speedup vs baseline: 2.4502x; 2.4502x over previous
//
#include <hip/hip_runtime.h>
#include <hip/hip_bf16.h>

#define Lc 4
#define Nc 50000
#define Ec 800000
#define Bc 16384
#define EDc 256
#define Kc 7
#define Mtot (Lc * Nc)      // 200000 nodes total
#define KDIM (EDc * Kc)     // 1792

#define BINW 512            // nodes per bin
#define BSH 9
#define FB 98               // bins per layer = ceil(50000/512)
#define NBINS (FB * Lc)     // 392
#define CAPc 12288          // csr capacity per bin (mean 8192)
#define CHUNK 8192          // edges per binfill block
#define FBLK 98             // ceil(Ec/CHUNK)
#define SCAP 160            // slots per (block,bin) cell: mean 84 + 8.4 sigma

#define PADTOT 33024        // 32768 sides + per-layer pad to 64
#define PADBIT (1 << 24)

typedef __attribute__((ext_vector_type(8))) short bf16x8;
typedef __attribute__((ext_vector_type(4))) float f32x4;

static __device__ __forceinline__ unsigned short f2bf(float f) {
    unsigned u = __float_as_uint(f);
    unsigned r = (u + 0x7fffu + ((u >> 16) & 1u)) >> 16;
    return (unsigned short)r;
}
static __device__ __forceinline__ float bf2f(unsigned short u) {
    return __uint_as_float(((unsigned)u) << 16);
}

// ---------------- prep: weight transposes + scratch zero -------------------

__global__ void k_prep(const float* __restrict__ conv_w, unsigned short* __restrict__ wbt,
                       const float* __restrict__ W2, unsigned short* __restrict__ w2t,
                       int* __restrict__ zeroRegion, int zn) {
    int bb = blockIdx.x;
    if (bb < 1792) {
        int i = bb * 256 + threadIdx.x;       // 458752
        int co = i / KDIM;
        int r = i % KDIM;
        int ci = r / Kc, k = r % Kc;
        wbt[(size_t)co * KDIM + k * EDc + ci] = f2bf(conv_w[i]);
    } else {
        int i = (bb - 1792) * 256 + threadIdx.x;  // 0..32767
        if (i < zn) zeroRegion[i] = 0;
        int l = i >> 13, r = i & 8191;
        int d = r >> 6, h = r & 63;
        w2t[i] = f2bf(W2[(size_t)(l * 64 + h) * 128 + d]);
    }
}

// mark sampled (layer,node) bitmap + per-layer sample counts + init ord
__global__ void k_mark(const int* __restrict__ now, const int* __restrict__ lnn,
                       const int* __restrict__ rnn, int* __restrict__ ord,
                       unsigned* __restrict__ bitmap, int* __restrict__ gcnt) {
    int b = blockIdx.x * 256 + threadIdx.x;   // exactly 16384 threads
    for (int p = b; p < PADTOT; p += 16384) ord[p] = PADBIT;
    int l = now[b];
    int a1 = l * Nc + lnn[b];
    atomicOr(&bitmap[a1 >> 5], 1u << (a1 & 31));
    int a2 = l * Nc + rnn[b];
    atomicOr(&bitmap[a2 >> 5], 1u << (a2 & 31));
    int lane = threadIdx.x & 63;
#pragma unroll
    for (int ll = 0; ll < 4; ll++) {
        unsigned long long m = __ballot(l == ll);
        if (m && lane == __builtin_ctzll(m)) atomicAdd(&gcnt[ll], __popcll(m));
    }
}

// ---------------- single-pass binned edge sort -----------------------------
// Each (block,bin) cell owns a fixed SCAP-slot segment: no histogram pre-pass,
// no global cursor reservation; write runs stay ~336B (round-10 lesson:
// run length, not occupancy, governs write amplification).

__global__ __launch_bounds__(512) void k_binfill(const int* __restrict__ ei,
                                                 int* __restrict__ blkCnt,
                                                 int* __restrict__ binned) {
    int l = blockIdx.y, bx = blockIdx.x;
    int e0 = bx * CHUNK;
    __shared__ int lcur[FB];
    if (threadIdx.x < FB) lcur[threadIdx.x] = 0;
    __syncthreads();
    const int* srcp = ei + (size_t)l * 2 * Ec;
    const int* dstp = srcp + Ec;
    int segBase = (l * FBLK + bx) * FB;
#pragma unroll
    for (int it = 0; it < CHUNK / 512; it++) {
        int idx = e0 + it * 512 + threadIdx.x;
        if (idx < Ec) {
            int d = dstp[idx], sv = srcp[idx];
            int t = d >> BSH;
            int slot = atomicAdd(&lcur[t], 1);
            if (slot < SCAP)
                binned[(size_t)(segBase + t) * SCAP + slot] = (sv << BSH) | (d & (BINW - 1));
        }
    }
    __syncthreads();
    if (threadIdx.x < FB) blkCnt[segBase + threadIdx.x] = min(lcur[threadIdx.x], SCAP);
}

// one block per bin: hist + rstart/cnt/dis/g + bitmap-filtered csr scatter
__global__ __launch_bounds__(512) void k_csr(const int* __restrict__ blkCnt,
                                             const int* __restrict__ binned,
                                             const float* __restrict__ x_nodes,
                                             const unsigned* __restrict__ bitmap,
                                             int* __restrict__ csr,
                                             int* __restrict__ rstart,
                                             int* __restrict__ cnt,
                                             float* __restrict__ dis,
                                             float* __restrict__ g) {
    int b = blockIdx.x;              // 0..NBINS-1
    int l = b / FB, gg = b % FB;
    int rs = b * CAPc;
    __shared__ int segc[FBLK];
    __shared__ int hist[BINW];
    if (threadIdx.x < FBLK) segc[threadIdx.x] = blkCnt[(l * FBLK + threadIdx.x) * FB + gg];
    hist[threadIdx.x] = 0;
    __syncthreads();
    const int PADN = FBLK * SCAP;    // 15680
    size_t binBase = (size_t)l * FBLK * FB + gg;
    for (int i = threadIdx.x; i < PADN; i += 512) {
        int seg = i / SCAP, sl = i - seg * SCAP;
        if (sl < segc[seg]) {
            int p = binned[(binBase + (size_t)seg * FB) * SCAP + sl];
            atomicAdd(&hist[p & (BINW - 1)], 1);
        }
    }
    __syncthreads();
    int lane = threadIdx.x & 63, wid = threadIdx.x >> 6;
    int v = hist[threadIdx.x];
    int x = v;
#pragma unroll
    for (int off = 1; off < 64; off <<= 1) {
        int y = __shfl_up(x, off);
        if (lane >= off) x += y;
    }
    __shared__ int ws[8];
    if (lane == 63) ws[wid] = x;
    __syncthreads();
    int carry = 0;
    for (int w = 0; w < wid; w++) carry += ws[w];
    int exc = x - v + carry;         // exclusive prefix within bin
    int n = gg * BINW + threadIdx.x;
    int n4 = l * Nc + n;
    if (n < Nc) {
        rstart[n4] = rs + exc;
        cnt[n4] = v;
        float dn = rsqrtf((float)v + 1.0f);   // +1 self loop
        dis[n4] = dn;
        g[n4] = dn * x_nodes[(size_t)l * Nc + n];
    }
    __syncthreads();                 // all reads of hist done
    hist[threadIdx.x] = rs + exc;    // reuse as cursor
    __syncthreads();
    int lbase = l * Nc + gg * BINW;
    for (int i = threadIdx.x; i < PADN; i += 512) {
        int seg = i / SCAP, sl = i - seg * SCAP;
        if (sl < segc[seg]) {
            unsigned p = (unsigned)binned[(binBase + (size_t)seg * FB) * SCAP + sl];
            int d = p & (BINW - 1);
            int nn4 = lbase + d;
            if ((bitmap[nn4 >> 5] >> (nn4 & 31)) & 1u) {   // only sampled dst rows
                int pos = atomicAdd(&hist[d], 1);
                csr[pos] = (int)(p >> BSH);
            }
        }
    }
}

// edge-parallel s aggregation + BN stats (per bin); packs ns = (dis, s)
__global__ __launch_bounds__(512) void k_s_bin(const int* __restrict__ blkCnt,
                                               const int* __restrict__ binned,
                                               const float* __restrict__ g,
                                               const float* __restrict__ dis,
                                               float2* __restrict__ ns,
                                               double* __restrict__ stats) {
    int b = blockIdx.x;              // 0..NBINS-1
    int l = b / FB, gg = b % FB;
    const float* gl = g + (size_t)l * Nc;
    __shared__ int segc[FBLK];
    __shared__ float acc[BINW];
    if (threadIdx.x < FBLK) segc[threadIdx.x] = blkCnt[(l * FBLK + threadIdx.x) * FB + gg];
    acc[threadIdx.x] = 0.f;
    __syncthreads();
    const int PADN = FBLK * SCAP;
    size_t binBase = (size_t)l * FBLK * FB + gg;
    for (int i = threadIdx.x; i < PADN; i += 512) {
        int seg = i / SCAP, sl = i - seg * SCAP;
        if (sl < segc[seg]) {
            unsigned p = (unsigned)binned[(binBase + (size_t)seg * FB) * SCAP + sl];
            atomicAdd(&acc[p & (BINW - 1)], gl[p >> BSH]);   // LDS fp32 atomic
        }
    }
    __syncthreads();
    int n = gg * BINW + threadIdx.x;
    int n4 = l * Nc + n;
    double v = 0.0, v2 = 0.0;
    if (n < Nc) {
        float dn = dis[n4];
        float sf = dn * (acc[threadIdx.x] + g[n4]);  // neighbors + self loop
        ns[n4] = make_float2(dn, sf);
        v = (double)sf;
        v2 = (double)sf * (double)sf;
    }
    for (int m = 32; m; m >>= 1) { v += __shfl_xor(v, m); v2 += __shfl_xor(v2, m); }
    __shared__ double r0[8], r1[8];
    int wid = threadIdx.x >> 6, lane = threadIdx.x & 63;
    if (lane == 0) { r0[wid] = v; r1[wid] = v2; }
    __syncthreads();
    if (threadIdx.x == 0) {
        double a = 0, bb = 0;
        for (int w = 0; w < 8; w++) { a += r0[w]; bb += r1[w]; }
        atomicAdd(&stats[l * 2 + 0], a);
        atomicAdd(&stats[l * 2 + 1], bb);
    }
}

// ---------------- side ordering + BN coefficient vector (fused) ------------

__global__ __launch_bounds__(256) void k_ordcvec(const int* __restrict__ now,
        const int* __restrict__ gcnt, int* __restrict__ gcur, int* __restrict__ ord,
        const double* __restrict__ stats, const float* __restrict__ W1,
        const float* __restrict__ gamma, float* __restrict__ cbuf) {
    if (blockIdx.x == 64) {          // cvec block
        int l = threadIdx.x >> 6, h = threadIdx.x & 63;
        double mean = stats[l * 2] / (double)Nc;
        double var = stats[l * 2 + 1] / (double)Nc - mean * mean;
        float w = W1[l * 64 + h];
        cbuf[l * 72 + h] = gamma[l * 64 + h] * w * rsqrtf((float)var * w * w + 1e-5f);
        if (h == 0) cbuf[l * 72 + 64] = (float)mean;
        return;
    }
    int b = blockIdx.x * 256 + threadIdx.x;   // exactly 16384
    int l = now[b];
    int segBase = 0;
    for (int ll = 0; ll < l; ll++) segBase += (2 * gcnt[ll] + 63) & ~63;
    int lane = threadIdx.x & 63;
#pragma unroll
    for (int ll = 0; ll < 4; ll++) {
        unsigned long long m = __ballot(l == ll);
        if (!m) continue;
        int ldr = __builtin_ctzll(m);
        int bs = 0;
        if (lane == ldr) bs = atomicAdd(&gcur[ll], __popcll(m));
        bs = __shfl(bs, ldr);
        if (l == ll) {
            int rk = __popcll(m & (lane ? ((1ull << lane) - 1) : 0ull));
            int sp = segBase + 2 * (bs + rk);
            ord[sp] = (2 * b) | (ll << 20);
            ord[sp + 1] = (2 * b + 1) | (ll << 20);
        }
    }
}

// ---------------- per-side aggregation (lane-parallel edge gather) ---------

__global__ __launch_bounds__(256) void k_agg(const int* __restrict__ ord,
        const int* __restrict__ lnn, const int* __restrict__ rnn,
        const int* __restrict__ rstart, const int* __restrict__ cnt,
        const int* __restrict__ csr, const float2* __restrict__ ns,
        const float* __restrict__ cbuf, const float* __restrict__ beta,
        unsigned short* __restrict__ acch) {
    int pos = blockIdx.x * 4 + (threadIdx.x >> 6);
    int lane = threadIdx.x & 63;
    int ordv = ord[pos];
    if (ordv & PADBIT) { acch[(size_t)pos * 64 + lane] = 0; return; }
    int side = ordv & 0xFFFFF;
    int l = (ordv >> 20) & 3;
    int b = side >> 1;
    int n = (side & 1) ? rnn[b] : lnn[b];
    int n4 = l * Nc + n;
    float c = cbuf[l * 72 + lane], mu = cbuf[l * 72 + 64], bt = beta[l * 64 + lane];
    const float2* nsl = ns + (size_t)l * Nc;
    int st = rstart[n4], deg = cnt[n4];
    float a = 0.f;
    for (int base = 0; base < deg; base += 64) {
        int e = base + lane;
        int sv = (e < deg) ? csr[st + e] : 0;        // coalesced vector load
        float nv = 0.f, fv = 0.f;
        if (e < deg) {
            float2 nf = nsl[sv];                     // 64 parallel gathers
            nv = nf.x; fv = nf.y;
        }
        int m = min(64, deg - base);
        for (int j = 0; j < m; j++) {
            float nj = __shfl(nv, j);
            float fj = __shfl(fv, j);
            a += nj * fmaxf(c * (fj - mu) + bt, 0.f);
        }
    }
    float2 nself = ns[n4];
    float hs = fmaxf(c * (nself.y - mu) + bt, 0.f);
    a = nself.x * a + nself.x * nself.x * hs;
    acch[(size_t)pos * 64 + lane] = f2bf(a);
}

// batched MFMA GEMM: [PADTOT x 64] @ W2[l][64 x 128] -> lsh (bf16)
__global__ __launch_bounds__(256) void k_embgemm(const unsigned short* __restrict__ acch,
        const int* __restrict__ ord, const unsigned short* __restrict__ w2t,
        const float* __restrict__ b2, unsigned short* __restrict__ lsh) {
    int t0 = blockIdx.x * 16;
    int wn = threadIdx.x >> 6, lane = threadIdx.x & 63;
    int lrow = lane & 15, lg = lane >> 4;
    int l = (ord[t0] >> 20) & 3;     // uniform layer for all valid rows in tile
    const unsigned short* ap = acch + (size_t)(t0 + lrow) * 64 + lg * 8;
    const unsigned short* bp = w2t + (size_t)(l * 128 + wn * 32 + lrow) * 64 + lg * 8;
    f32x4 acc[2] = {};
#pragma unroll
    for (int kt = 0; kt < 2; kt++) {
        bf16x8 a = *(const bf16x8*)(ap + kt * 32);
        bf16x8 b0 = *(const bf16x8*)(bp + kt * 32);
        bf16x8 b1 = *(const bf16x8*)(bp + 16 * 64 + kt * 32);
        acc[0] = __builtin_amdgcn_mfma_f32_16x16x32_bf16(a, b0, acc[0], 0, 0, 0);
        acc[1] = __builtin_amdgcn_mfma_f32_16x16x32_bf16(a, b1, acc[1], 0, 0, 0);
    }
#pragma unroll
    for (int r = 0; r < 4; r++) {
        int pos = t0 + lg * 4 + r;
        int ordv = ord[pos];
        if (ordv & PADBIT) continue;
        int side = ordv & 0xFFFFF;
        size_t base = (size_t)(side >> 1) * 256 + (side & 1) * 128;
#pragma unroll
        for (int ni = 0; ni < 2; ni++) {
            int n = wn * 32 + ni * 16 + lrow;
            lsh[base + n] = f2bf(acc[ni][r] + b2[l * 128 + n]);
        }
    }
}

// ---------------- fused conv1d MFMA GEMM + ortho/link/disc epilogue --------

__global__ __launch_bounds__(512, 1) void k_convfinal(const unsigned short* __restrict__ lsh,
        const unsigned short* __restrict__ wbt, const float* __restrict__ cb,
        const float* __restrict__ lc_w, const float* __restrict__ lc_b,
        const float* __restrict__ link_w, const float* __restrict__ link_b,
        float* __restrict__ out) {
    __shared__ unsigned short lsa[70 * EDc];   // 35840 B (bf16 ls window)
    __shared__ float shs[64][EDc];             // 65536 B (f32 shared rows)
    int b0 = blockIdx.x * 64;
    int wid = threadIdx.x >> 6, lane = threadIdx.x & 63;
    int lrow = lane & 15, lg = lane >> 4;

    for (int idx = threadIdx.x; idx < 70 * 32; idx += 512) {
        int r = idx >> 5, c = idx & 31;
        int grow = b0 - 3 + r;
        uint4 v = make_uint4(0u, 0u, 0u, 0u);
        if ((unsigned)grow < (unsigned)Bc)
            v = *(const uint4*)(lsh + (size_t)grow * EDc + c * 8);
        int byte = (r * 512 + c * 16) ^ ((r & 7) << 4);
        *(uint4*)((char*)lsa + byte) = v;
    }
    __syncthreads();

    const unsigned short* w0 = wbt + (size_t)(wid * 32 + lrow) * KDIM + lg * 8;

    f32x4 acc[4][2] = {};
    bf16x8 br0[8][2], br1[8][2];

#pragma unroll
    for (int tt = 0; tt < 8; tt++)
#pragma unroll
        for (int ni = 0; ni < 2; ni++)
            br0[tt][ni] = *(const bf16x8*)(w0 + ni * 16 * KDIM + tt * 32);

#pragma unroll
    for (int k = 0; k < Kc; k++) {
        if (k < Kc - 1) {
#pragma unroll
            for (int tt = 0; tt < 8; tt++)
#pragma unroll
                for (int ni = 0; ni < 2; ni++) {
                    bf16x8 v = *(const bf16x8*)(w0 + ni * 16 * KDIM + (k + 1) * 256 + tt * 32);
                    if (k & 1) br0[tt][ni] = v; else br1[tt][ni] = v;
                }
        }
#pragma unroll
        for (int tt = 0; tt < 8; tt++) {
            bf16x8 a[4];
#pragma unroll
            for (int mi = 0; mi < 4; mi++) {
                int l = mi * 16 + lrow + k;
                a[mi] = *(const bf16x8*)((const char*)lsa + l * 512
                        + ((lg * 16 + tt * 64) ^ ((l & 7) << 4)));
            }
#pragma unroll
            for (int mi = 0; mi < 4; mi++)
#pragma unroll
                for (int ni = 0; ni < 2; ni++) {
                    bf16x8 bv = (k & 1) ? br1[tt][ni] : br0[tt][ni];
                    acc[mi][ni] = __builtin_amdgcn_mfma_f32_16x16x32_bf16(
                        a[mi], bv, acc[mi][ni], 0, 0, 0);
                }
        }
    }

    // epilogue: relu(acc+bias) -> shs (f32)
#pragma unroll
    for (int mi = 0; mi < 4; mi++) {
        int rrow = mi * 16 + lg * 4;
#pragma unroll
        for (int ni = 0; ni < 2; ni++) {
            int co = wid * 32 + ni * 16 + lrow;
            float bias = cb[co];
#pragma unroll
            for (int r = 0; r < 4; r++)
                shs[rrow + r][co] = fmaxf(acc[mi][ni][r] + bias, 0.0f);
        }
    }
    __syncthreads();

    // final: 8 waves x 8 rows — ortho + link + disc
    for (int rr = 0; rr < 8; rr++) {
        int row = wid * 8 + rr;
        int b = b0 + row;
        int lr = row + 3;
        int swz = (lr & 7) << 4;
        float lsv[4], shv[4];
        float dot = 0.f, nrm = 0.f;
#pragma unroll
        for (int i = 0; i < 4; i++) {
            int ci = lane + i * 64;
            lsv[i] = bf2f(*(const unsigned short*)((const char*)lsa + lr * 512 + ((ci * 2) ^ swz)));
            shv[i] = shs[row][ci];
            dot += lsv[i] * shv[i];
            nrm += shv[i] * shv[i];
        }
        for (int m = 32; m; m >>= 1) { dot += __shfl_xor(dot, m); nrm += __shfl_xor(nrm, m); }
        float coef = dot / (nrm + 1e-12f);
        float p0 = 0.f, p1 = 0.f, d0 = 0.f, d1 = 0.f, d2 = 0.f, d3 = 0.f;
#pragma unroll
        for (int i = 0; i < 4; i++) {
            int ci = lane + i * 64;
            float e = lsv[i] - coef * shv[i] + shv[i];
            p0 += e * link_w[ci * 2];
            p1 += e * link_w[ci * 2 + 1];
            d0 += shv[i] * lc_w[ci * 4];
            d1 += shv[i] * lc_w[ci * 4 + 1];
            d2 += shv[i] * lc_w[ci * 4 + 2];
            d3 += shv[i] * lc_w[ci * 4 + 3];
        }
        for (int m = 32; m; m >>= 1) {
            p0 += __shfl_xor(p0, m); p1 += __shfl_xor(p1, m);
            d0 += __shfl_xor(d0, m); d1 += __shfl_xor(d1, m);
            d2 += __shfl_xor(d2, m); d3 += __shfl_xor(d3, m);
        }
        if (lane == 0) {
            out[b * 2]     = p0 + link_b[0];
            out[b * 2 + 1] = p1 + link_b[1];
            float* dd = out + 2 * Bc;
            dd[b * 4]     = d0 + lc_b[0];
            dd[b * 4 + 1] = d1 + lc_b[1];
            dd[b * 4 + 2] = d2 + lc_b[2];
            dd[b * 4 + 3] = d3 + lc_b[3];
        }
    }
}

// ---------------- launch ----------------

extern "C" void kernel_launch(void* const* d_in, const int* in_sizes, int n_in,
                              void* d_out, int out_size, void* d_ws, size_t ws_size,
                              hipStream_t stream) {
    const float* x_nodes    = (const float*)d_in[0];
    const int*   edge_index = (const int*)d_in[1];
    const float* W1   = (const float*)d_in[2];
    // d_in[3] = b1 (cancels in BN)
    const float* gamma = (const float*)d_in[4];
    const float* beta  = (const float*)d_in[5];
    const float* W2   = (const float*)d_in[6];
    const float* b2   = (const float*)d_in[7];
    const float* conv_w = (const float*)d_in[8];
    const float* conv_b = (const float*)d_in[9];
    const float* lc_w   = (const float*)d_in[10];
    const float* lc_b   = (const float*)d_in[11];
    const float* link_w = (const float*)d_in[12];
    const float* link_b = (const float*)d_in[13];
    const int* now = (const int*)d_in[14];
    const int* ln  = (const int*)d_in[15];
    const int* rn  = (const int*)d_in[16];
    float* out = (float*)d_out;

    char* base = (char*)d_ws;
    size_t off = 0;
    auto carve = [&](size_t bytes) {
        void* p = base + off;
        off = (off + bytes + 255) & ~(size_t)255;
        return p;
    };
    // zero-init region: bitmap .. stats (zeroed inside k_prep)
    unsigned* bitmap = (unsigned*)carve(6272 * 4);
    int*      gcnt   = (int*)carve(4 * 4);
    int*      gcur   = (int*)carve(4 * 4);
    double*   stats  = (double*)carve(8 * 8);
    // rest (no zeroing needed)
    int*    blkCnt   = (int*)carve((size_t)Lc * FBLK * FB * 4);
    int*    binned   = (int*)carve((size_t)Lc * FBLK * FB * SCAP * 4);
    int*    rstart   = (int*)carve((size_t)Mtot * 4);
    int*    cnt      = (int*)carve((size_t)Mtot * 4);
    int*    csr      = (int*)carve((size_t)NBINS * CAPc * 4);
    float*  dis      = (float*)carve((size_t)Mtot * 4);
    float*  g        = (float*)carve((size_t)Mtot * 4);
    float2* ns       = (float2*)carve((size_t)Mtot * 8);
    float*  cbuf     = (float*)carve(Lc * 72 * 4);
    int*    ord      = (int*)carve((size_t)PADTOT * 4);
    unsigned short* acch = (unsigned short*)carve((size_t)PADTOT * 64 * 2);
    unsigned short* lsh  = (unsigned short*)carve((size_t)Bc * 256 * 2);
    unsigned short* wbt  = (unsigned short*)carve((size_t)EDc * KDIM * 2);
    unsigned short* w2t  = (unsigned short*)carve((size_t)Lc * 128 * 64 * 2);
    (void)ws_size;

    int zn = (int)(((char*)(stats + 8) - (char*)bitmap) / 4);

    k_prep<<<1920, 256, 0, stream>>>(conv_w, wbt, W2, w2t, (int*)bitmap, zn);
    k_mark<<<64, 256, 0, stream>>>(now, ln, rn, ord, bitmap, gcnt);
    k_binfill<<<dim3(FBLK, Lc), 512, 0, stream>>>(edge_index, blkCnt, binned);
    k_csr<<<NBINS, 512, 0, stream>>>(blkCnt, binned, x_nodes, bitmap,
                                     csr, rstart, cnt, dis, g);
    k_s_bin<<<NBINS, 512, 0, stream>>>(blkCnt, binned, g, dis, ns, stats);
    k_ordcvec<<<65, 256, 0, stream>>>(now, gcnt, gcur, ord, stats, W1, gamma, cbuf);
    k_agg<<<PADTOT / 4, 256, 0, stream>>>(ord, ln, rn, rstart, cnt, csr, ns,
                                          cbuf, beta, acch);
    k_embgemm<<<PADTOT / 16, 256, 0, stream>>>(acch, ord, w2t, b2, lsh);
    k_convfinal<<<Bc / 64, 512, 0, stream>>>(lsh, wbt, conv_b,
                                             lc_w, lc_b, link_w, link_b, out);
}